// Round 4
// baseline (376.241 us; speedup 1.0000x reference)
//
#include <hip/hip_runtime.h>
#include <hip/hip_bf16.h>
#include <cstdint>
#include <cstddef>

// BitNet b1.58 attention block: B=2 S=2048 D=2048 H=16 HD=128.
// All quantized matmuls done in bf16 MFMA (exact: int8 x ternary, sums < 2^24).

#define BB 2
#define SS 2048
#define DD 2048
#define HH 16
#define HDD 128
#define MM (BB*SS)   // 4096 token rows

typedef __attribute__((ext_vector_type(8))) short bf16x8;
typedef __attribute__((ext_vector_type(4))) float f32x4;
typedef unsigned short u16;
typedef unsigned int   u32;

#define MFMA(a,b,c) __builtin_amdgcn_mfma_f32_16x16x32_bf16(a,b,c,0,0,0)

static __device__ __forceinline__ u16 f2bf(float f) {
  // round-to-nearest-even float->bf16 (no NaN inputs here)
  u32 x = __float_as_uint(f);
  u32 r = x + 0x7fffu + ((x >> 16) & 1u);
  return (u16)(r >> 16);
}

// async global->LDS, 16B per lane; LDS dest must be linear (base + lane*16)
static __device__ __forceinline__ void gl_lds16(const u16* g, u16* l) {
  __builtin_amdgcn_global_load_lds((const __attribute__((address_space(1))) void*)g,
                                   (__attribute__((address_space(3))) void*)l, 16, 0, 0);
}

// ---------------- weight scale: deterministic two-stage |w| mean in f64 ----
__global__ void k_wabs_partial(const float* __restrict__ w0, const float* __restrict__ w1,
                               const float* __restrict__ w2, const float* __restrict__ w3,
                               double* __restrict__ part) {
  int m = blockIdx.x >> 8, blk = blockIdx.x & 255;
  const float* w = (m == 0) ? w0 : (m == 1) ? w1 : (m == 2) ? w2 : w3;
  const float* p = w + (size_t)blk * 16384;
  double s = 0.0;
  for (int i = threadIdx.x * 4; i < 16384; i += 1024) {
    float4 v = *(const float4*)(p + i);
    s += (double)fabsf(v.x) + (double)fabsf(v.y) + (double)fabsf(v.z) + (double)fabsf(v.w);
  }
  __shared__ double red[256];
  red[threadIdx.x] = s;
  __syncthreads();
  for (int off = 128; off > 0; off >>= 1) {
    if ((int)threadIdx.x < off) red[threadIdx.x] += red[threadIdx.x + off];
    __syncthreads();
  }
  if (threadIdx.x == 0) part[m * 256 + blk] = red[0];
}

__global__ void k_wscale_final(const double* __restrict__ part, float* __restrict__ scales) {
  int m = threadIdx.x;
  if (m < 4) {
    double s = 0.0;
    for (int i = 0; i < 256; i++) s += part[m * 256 + i];
    float v = (float)(s * (1.0 / 4194304.0));   // /(D*D), power of 2: exact
    scales[m] = fmaxf(v, 1e-6f);
  }
}

// ---------------- ternary weight quant -> bf16 ------------------------------
__global__ void k_wquant(const float* __restrict__ w0, const float* __restrict__ w1,
                         const float* __restrict__ w2, const float* __restrict__ w3,
                         u16* __restrict__ wq, const float* __restrict__ scales) {
  int m = blockIdx.y;
  const float* w = (m == 0) ? w0 : (m == 1) ? w1 : (m == 2) ? w2 : w3;
  float ws = scales[m];
  size_t i = ((size_t)blockIdx.x * 256 + threadIdx.x) * 4;
  float4 v = *(const float4*)(w + i);
  u16* o = wq + (size_t)m * DD * DD + i;
  float a = fminf(1.f, fmaxf(-1.f, rintf(v.x / ws)));
  float b = fminf(1.f, fmaxf(-1.f, rintf(v.y / ws)));
  float c = fminf(1.f, fmaxf(-1.f, rintf(v.z / ws)));
  float d = fminf(1.f, fmaxf(-1.f, rintf(v.w / ws)));
  ushort4 pk;
  pk.x = f2bf(a); pk.y = f2bf(b); pk.z = f2bf(c); pk.w = f2bf(d);
  *(ushort4*)o = pk;
}

// ---------------- per-token absmax + inv scale ------------------------------
__global__ void k_rowamax(const float* __restrict__ x, float* __restrict__ amax,
                          float* __restrict__ sinv) {
  int row = blockIdx.x;
  const float* p = x + (size_t)row * DD;
  float m = 0.f;
  for (int i = threadIdx.x * 4; i < DD; i += 1024) {
    float4 v = *(const float4*)(p + i);
    m = fmaxf(m, fmaxf(fmaxf(fabsf(v.x), fabsf(v.y)), fmaxf(fabsf(v.z), fabsf(v.w))));
  }
  m = fmaxf(m, __shfl_xor(m, 1));  m = fmaxf(m, __shfl_xor(m, 2));
  m = fmaxf(m, __shfl_xor(m, 4));  m = fmaxf(m, __shfl_xor(m, 8));
  m = fmaxf(m, __shfl_xor(m, 16)); m = fmaxf(m, __shfl_xor(m, 32));
  __shared__ float red[4];
  if ((threadIdx.x & 63) == 0) red[threadIdx.x >> 6] = m;
  __syncthreads();
  if (threadIdx.x == 0) {
    m = fmaxf(fmaxf(red[0], red[1]), fmaxf(red[2], red[3]));
    m = fmaxf(m, 1e-8f);            // clip(amax, 1e-8)
    amax[row] = m;
    sinv[row] = 127.0f / m;         // matches ref: QMAX / a_max
  }
}

// ---------------- int8-range activation quant -> bf16 -----------------------
__global__ void k_aquant(const float* __restrict__ x, u16* __restrict__ xq,
                         const float* __restrict__ sinv) {
  size_t i = ((size_t)blockIdx.x * 256 + threadIdx.x) * 4;
  int row = (int)(i >> 11);  // /2048
  float s = sinv[row];
  float4 v = *(const float4*)(x + i);
  float a = fminf(127.f, fmaxf(-127.f, rintf(v.x * s)));
  float b = fminf(127.f, fmaxf(-127.f, rintf(v.y * s)));
  float c = fminf(127.f, fmaxf(-127.f, rintf(v.z * s)));
  float d = fminf(127.f, fmaxf(-127.f, rintf(v.w * s)));
  ushort4 pk;
  pk.x = f2bf(a); pk.y = f2bf(b); pk.z = f2bf(c); pk.w = f2bf(d);
  *(ushort4*)(xq + i) = pk;
}

// ---------------- bf16 MFMA GEMM: C[m][n] = sum_k A[m][k]*Bw[n][k] ----------
// 256x128 tile, BK=64, 8 waves (4x2), per-wave 64x64. Triple-buffered LDS
// (144KB) staged via global_load_lds width-16 into linear LDS with XOR-16B-
// block swizzle (pre-swizzled source). Counted vmcnt(6): tile t+2 loads stay
// in flight across the per-tile raw s_barrier (never drain to 0 mid-loop).
// OB: fused QKV (N=6144 over stacked weights, bf16 out); else f32 out.
template<bool OB>
__global__ __launch_bounds__(512) void k_gemm(const u16* __restrict__ A, const u16* __restrict__ Bw,
                                              const float* __restrict__ amax,
                                              const float* __restrict__ scales, int sbase,
                                              void* __restrict__ outv) {
  __shared__ u16 As[3][256 * 64];
  __shared__ u16 Bs[3][128 * 64];
  // XCD-bijective swizzle (nwg % 8 == 0): XCD x owns a contiguous bn-range
  int cpx = gridDim.x >> 3;
  int id = blockIdx.x;
  int tile = (id & 7) * cpx + (id >> 3);
  int bm = tile & 15, bn = tile >> 4;          // column-major: B-panel stays in XCD L2
  int t = threadIdx.x, w = t >> 6, l = t & 63;
  int wr = w >> 1, wc = w & 1;
  int l15 = l & 15, lh = l >> 4;
  int trow = t >> 3;
  int acol = (((t & 7) ^ (trow & 7)) * 8);     // pre-swizzled source column
  const u16* Ab = A  + (size_t)(bm * 256) * DD;
  const u16* Bb = Bw + (size_t)(bn * 128) * DD;

#define STAGE(kb_, buf_) do {                                                           \
    const u16* As_ = Ab + (size_t)(kb_) * 64;                                           \
    const u16* Bs_ = Bb + (size_t)(kb_) * 64;                                           \
    _Pragma("unroll")                                                                   \
    for (int i_ = 0; i_ < 4; i_++)                                                      \
      gl_lds16(As_ + (size_t)(i_ * 64 + trow) * DD + acol, &As[buf_][(i_ * 512 + t) * 8]); \
    _Pragma("unroll")                                                                   \
    for (int j_ = 0; j_ < 2; j_++)                                                      \
      gl_lds16(Bs_ + (size_t)(j_ * 64 + trow) * DD + acol, &Bs[buf_][(j_ * 512 + t) * 8]); \
  } while (0)

  f32x4 acc[4][4] = {};
  STAGE(0, 0);
  STAGE(1, 1);
  asm volatile("s_waitcnt vmcnt(6)" ::: "memory");
  asm volatile("s_barrier" ::: "memory");
  for (int kb = 0; kb < 32; kb++) {
    int cur = kb % 3;
    if (kb + 2 < 32) STAGE(kb + 2, (kb + 2) % 3);
    const u16* Ac = As[cur];
    const u16* Bc = Bs[cur];
    #pragma unroll
    for (int ks = 0; ks < 2; ks++) {
      bf16x8 af[4], bfr[4];
      #pragma unroll
      for (int m = 0; m < 4; m++)
        af[m] = *(const bf16x8*)(Ac + (wr * 64 + m * 16 + l15) * 64 + (((ks * 4 + lh) ^ (l15 & 7)) * 8));
      #pragma unroll
      for (int n = 0; n < 4; n++)
        bfr[n] = *(const bf16x8*)(Bc + (wc * 64 + n * 16 + l15) * 64 + (((ks * 4 + lh) ^ (l15 & 7)) * 8));
      __builtin_amdgcn_s_setprio(1);
      #pragma unroll
      for (int m = 0; m < 4; m++)
        #pragma unroll
        for (int n = 0; n < 4; n++)
          acc[m][n] = MFMA(af[m], bfr[n], acc[m][n]);
      __builtin_amdgcn_s_setprio(0);
    }
    if (kb < 31) {
      asm volatile("s_waitcnt lgkmcnt(0)" ::: "memory");   // our reads of cur retired
      if (kb < 30) asm volatile("s_waitcnt vmcnt(6)" ::: "memory");  // t+1 landed, t+2 in flight
      else         asm volatile("s_waitcnt vmcnt(0)" ::: "memory");  // tail: t31 landed
      asm volatile("s_barrier" ::: "memory");
    }
  }
#undef STAGE
  int gcol0 = bn * 128;
  int mz = OB ? (gcol0 >> 11) : 0;
  int lcol0 = OB ? (gcol0 & 2047) : gcol0;
  float wsc = scales[sbase + mz];
  u16*   outb = (u16*)outv + (size_t)mz * MM * DD;
  float* outf = (float*)outv;
  #pragma unroll
  for (int i = 0; i < 4; i++) {
    int row0 = bm * 256 + wr * 64 + i * 16 + lh * 4;
    #pragma unroll
    for (int r = 0; r < 4; r++) {
      float sc = (wsc * amax[row0 + r]) / 127.0f;
      #pragma unroll
      for (int j = 0; j < 4; j++) {
        int col = lcol0 + wc * 64 + j * 16 + l15;
        float y = acc[i][j][r] * sc;
        if (OB) outb[(size_t)(row0 + r) * DD + col] = f2bf(y);
        else    outf[(size_t)(row0 + r) * DD + col] = y;
      }
    }
  }
}

// ---------------- V transpose: v[b*S+s][h*128+d] -> vt[(b*16+h)*128+d][s] ---
__global__ __launch_bounds__(256) void k_vtrans(const u16* __restrict__ v, u16* __restrict__ vt) {
  __shared__ u16 tile[64][72];
  int sb = blockIdx.x;           // S/64
  int db = blockIdx.y;           // HD/64
  int bh = blockIdx.z;           // B*H
  int b = bh >> 4, h = bh & 15;
  int t = threadIdx.x;
  int ls = t >> 2, ld0 = (t & 3) * 16;
  const u16* src = v + (size_t)(b * SS + sb * 64 + ls) * DD + h * HDD + db * 64 + ld0;
  *(int4*)(&tile[ls][ld0])     = *(const int4*)(src);
  *(int4*)(&tile[ls][ld0 + 8]) = *(const int4*)(src + 8);
  __syncthreads();
  int d = t >> 2, s0 = (t & 3) * 16;
  u16 tmp[16];
  #pragma unroll
  for (int k = 0; k < 16; k++) tmp[k] = tile[s0 + k][d];
  u16* dst = vt + (size_t)((bh * HDD) + db * 64 + d) * SS + sb * 64 + s0;
  *(int4*)(dst)     = *(const int4*)(tmp);
  *(int4*)(dst + 8) = *(const int4*)(tmp + 8);
}

// ---------------- causal flash attention ------------------------------------
// 4 waves x 16 q-rows (QBLK=64), KVBLK=64. K-tile + V^T-tile staged via
// global_load_lds into linear LDS with XOR-swizzled 16B blocks; fragments via
// conflict-free ds_read_b128. P routed through per-wave padded LDS.
// Grid: 1024 blocks, XCD-swizzled (4 heads per XCD's L2).
__global__ __launch_bounds__(256) void k_attn(const u16* __restrict__ Q, const u16* __restrict__ K,
                                              const u16* __restrict__ VT, float* __restrict__ O) {
  __shared__ u16 Ks[64 * 128];   // [s][d]  256B rows, swizzled blocks
  __shared__ u16 Vs[128 * 64];   // [d][s]  128B rows, swizzled blocks
  __shared__ u16 Ps[4 * 16 * 72];
  int id = blockIdx.x;
  int orig = ((id & 7) << 7) | (id >> 3);   // bijective: XCD x -> bh 4x..4x+3
  int qb = orig & 31, bh = orig >> 5;
  int b = bh >> 4, h = bh & 15;
  int t = threadIdx.x, w = t >> 6, l = t & 63;
  int l15 = l & 15, lh = l >> 4;
  size_t base = (size_t)(b * SS) * DD + h * HDD;
  const u16* vtb = VT + (size_t)bh * HDD * SS;
  u16* Pw = Ps + w * 16 * 72;
  bf16x8 qf[4];
  {
    const u16* qp = Q + base + (size_t)(qb * 64 + w * 16 + l15) * DD + lh * 8;
    #pragma unroll
    for (int kt = 0; kt < 4; kt++) qf[kt] = *(const bf16x8*)(qp + kt * 32);
  }
  f32x4 cacc[8] = {};
  float mrun[4], lrun[4];
  #pragma unroll
  for (int r = 0; r < 4; r++) { mrun[r] = -INFINITY; lrun[r] = 0.f; }
  const float sc = 0.08838834764831845f;  // 1/sqrt(128)
  // staging slots (K: 16 blocks/row; VT: 8 blocks/row), source pre-swizzled
  int ksr[4], ksc[4], vsr[4], vsc[4];
  #pragma unroll
  for (int i = 0; i < 4; i++) {
    int s = i * 256 + t;
    ksr[i] = s >> 4; ksc[i] = (((t & 15) ^ (ksr[i] & 7)) * 8);
    vsr[i] = s >> 3; vsc[i] = (((t & 7)  ^ (vsr[i] & 7)) * 8);
  }
  for (int kb = 0; kb <= qb; kb++) {
    #pragma unroll
    for (int i = 0; i < 4; i++) {
      gl_lds16(K + base + (size_t)(kb * 64 + ksr[i]) * DD + ksc[i], Ks + (size_t)(i * 256 + t) * 8);
      gl_lds16(vtb + (size_t)vsr[i] * SS + kb * 64 + vsc[i],        Vs + (size_t)(i * 256 + t) * 8);
    }
    __syncthreads();
    // S = Q K^T : B-frags from swizzled Ks
    f32x4 sf[4] = {};
    #pragma unroll
    for (int nt = 0; nt < 4; nt++) {
      #pragma unroll
      for (int kt = 0; kt < 4; kt++) {
        bf16x8 kf = *(const bf16x8*)(Ks + (nt * 16 + l15) * 128 + (((kt * 4 + lh) ^ (l15 & 7)) * 8));
        sf[nt] = MFMA(qf[kt], kf, sf[nt]);
      }
    }
    // scale + causal mask (only the diagonal tile needs masking)
    bool diag = (kb == qb);
    #pragma unroll
    for (int nt = 0; nt < 4; nt++) {
      #pragma unroll
      for (int r = 0; r < 4; r++) {
        float v = sf[nt][r] * sc;
        if (diag && (nt * 16 + l15) > (w * 16 + lh * 4 + r)) v = -1e30f;
        sf[nt][r] = v;
      }
    }
    // online softmax: rows live across the 16 l15-lanes of each lh group
    #pragma unroll
    for (int r = 0; r < 4; r++) {
      float mx = fmaxf(fmaxf(sf[0][r], sf[1][r]), fmaxf(sf[2][r], sf[3][r]));
      mx = fmaxf(mx, __shfl_xor(mx, 1)); mx = fmaxf(mx, __shfl_xor(mx, 2));
      mx = fmaxf(mx, __shfl_xor(mx, 4)); mx = fmaxf(mx, __shfl_xor(mx, 8));
      float mnew = fmaxf(mrun[r], mx);
      float alpha = __expf(mrun[r] - mnew);
      float s0 = 0.f;
      #pragma unroll
      for (int nt = 0; nt < 4; nt++) { float pv = __expf(sf[nt][r] - mnew); sf[nt][r] = pv; s0 += pv; }
      s0 += __shfl_xor(s0, 1); s0 += __shfl_xor(s0, 2);
      s0 += __shfl_xor(s0, 4); s0 += __shfl_xor(s0, 8);
      lrun[r] = lrun[r] * alpha + s0;
      mrun[r] = mnew;
      #pragma unroll
      for (int n2 = 0; n2 < 8; n2++) cacc[n2][r] *= alpha;
    }
    // P -> per-wave LDS (C-layout -> A-layout), then PV from swizzled Vs
    #pragma unroll
    for (int r = 0; r < 4; r++)
      #pragma unroll
      for (int nt = 0; nt < 4; nt++)
        Pw[(lh * 4 + r) * 72 + nt * 16 + l15] = f2bf(sf[nt][r]);
    #pragma unroll
    for (int ks = 0; ks < 2; ks++) {
      bf16x8 pf = *(const bf16x8*)(Pw + l15 * 72 + ks * 32 + lh * 8);
      #pragma unroll
      for (int n2 = 0; n2 < 8; n2++) {
        bf16x8 vf = *(const bf16x8*)(Vs + (n2 * 16 + l15) * 64 + (((ks * 4 + lh) ^ (l15 & 7)) * 8));
        cacc[n2] = MFMA(pf, vf, cacc[n2]);
      }
    }
    __syncthreads();
  }
  #pragma unroll
  for (int r = 0; r < 4; r++) {
    float inv = 1.0f / lrun[r];
    float* op = O + base + (size_t)(qb * 64 + w * 16 + lh * 4 + r) * DD;
    #pragma unroll
    for (int n2 = 0; n2 < 8; n2++) op[n2 * 16 + l15] = cacc[n2][r] * inv;
  }
}

// ---------------- launch ----------------------------------------------------
// ws layout (bytes), total ~134.4 MB:
//   0        scales (4 f32)        256      partials (1024 f64)
//   16384    amax_x   32768 sinv_x   49152 amax_ctx   65536 sinv_ctx
//   131072   w_q bf16 (4 x D*D)  = 33,554,432
//   33685504 x_q bf16 (M*D)      = 16,777,216   (reused as V^T, then ctx_q)
//   50462720 q bf16 | 67239936 k | 84017152 v   (16,777,216 each, contiguous)
//   100794368 ctx f32            = 33,554,432
extern "C" void kernel_launch(void* const* d_in, const int* in_sizes, int n_in,
                              void* d_out, int out_size, void* d_ws, size_t ws_size,
                              hipStream_t stream) {
  const float* x  = (const float*)d_in[0];
  const float* wq = (const float*)d_in[1];
  const float* wk = (const float*)d_in[2];
  const float* wv = (const float*)d_in[3];
  const float* wo = (const float*)d_in[4];
  char* ws = (char*)d_ws;
  float*  scales = (float*)(ws + 0);
  double* part   = (double*)(ws + 256);
  float*  amaxx  = (float*)(ws + 16384);
  float*  sxinv  = (float*)(ws + 32768);
  float*  amaxc  = (float*)(ws + 49152);
  float*  scinv  = (float*)(ws + 65536);
  u16*    wqq    = (u16*)(ws + 131072);
  u16*    xq     = (u16*)(ws + 33685504);   // reused as V^T, then ctx_q
  u16*    qb     = (u16*)(ws + 50462720);
  u16*    kb     = (u16*)(ws + 67239936);
  u16*    vb     = (u16*)(ws + 84017152);
  float*  ctx    = (float*)(ws + 100794368);
  (void)in_sizes; (void)n_in; (void)out_size; (void)ws_size;

  k_wabs_partial<<<1024, 256, 0, stream>>>(wq, wk, wv, wo, part);
  k_wscale_final<<<1, 64, 0, stream>>>(part, scales);
  k_wquant<<<dim3(4096, 4), 256, 0, stream>>>(wq, wk, wv, wo, wqq, scales);
  k_rowamax<<<MM, 256, 0, stream>>>(x, amaxx, sxinv);
  k_aquant<<<8192, 256, 0, stream>>>(x, xq, sxinv);
  // fused QKV projection: one GEMM, M=4096 x N=6144 over stacked Wq/Wk/Wv;
  // q/k/v outputs are contiguous so mz picks the buffer. 768 blocks = 3/CU.
  k_gemm<true><<<768, 512, 0, stream>>>(xq, wqq, amaxx, scales, 0, (void*)qb);
  // V^T into the (now dead) xq region; then LDS-staged flash attention
  k_vtrans<<<dim3(32, 2, 32), 256, 0, stream>>>(vb, xq);
  k_attn<<<1024, 256, 0, stream>>>(qb, kb, xq, ctx);
  k_rowamax<<<MM, 256, 0, stream>>>(ctx, amaxc, scinv);
  k_aquant<<<8192, 256, 0, stream>>>(ctx, xq, scinv);  // ctx_q overwrites V^T (attn done)
  k_gemm<false><<<256, 512, 0, stream>>>(xq, wqq + (size_t)3 * DD * DD, amaxc, scales, 3, d_out);
}

// Round 5
// 327.939 us; speedup vs baseline: 1.1473x; 1.1473x over previous
//
#include <hip/hip_runtime.h>
#include <hip/hip_bf16.h>
#include <cstdint>
#include <cstddef>

// BitNet b1.58 attention block: B=2 S=2048 D=2048 H=16 HD=128.
// All quantized matmuls done in bf16 MFMA (exact: int8 x ternary, sums < 2^24).

#define BB 2
#define SS 2048
#define DD 2048
#define HH 16
#define HDD 128
#define MM (BB*SS)   // 4096 token rows

typedef __attribute__((ext_vector_type(8))) short bf16x8;
typedef __attribute__((ext_vector_type(4))) float f32x4;
typedef unsigned short u16;
typedef unsigned int   u32;

#define MFMA(a,b,c) __builtin_amdgcn_mfma_f32_16x16x32_bf16(a,b,c,0,0,0)

static __device__ __forceinline__ u16 f2bf(float f) {
  // round-to-nearest-even float->bf16 (no NaN inputs here)
  u32 x = __float_as_uint(f);
  u32 r = x + 0x7fffu + ((x >> 16) & 1u);
  return (u16)(r >> 16);
}

// async global->LDS, 16B per lane; LDS dest must be linear (base + lane*16)
static __device__ __forceinline__ void gl_lds16(const u16* g, u16* l) {
  __builtin_amdgcn_global_load_lds((const __attribute__((address_space(1))) void*)g,
                                   (__attribute__((address_space(3))) void*)l, 16, 0, 0);
}

// ---------------- weight scale: deterministic two-stage |w| mean in f64 ----
__global__ void k_wabs_partial(const float* __restrict__ w0, const float* __restrict__ w1,
                               const float* __restrict__ w2, const float* __restrict__ w3,
                               double* __restrict__ part) {
  int m = blockIdx.x >> 8, blk = blockIdx.x & 255;
  const float* w = (m == 0) ? w0 : (m == 1) ? w1 : (m == 2) ? w2 : w3;
  const float* p = w + (size_t)blk * 16384;
  double s = 0.0;
  for (int i = threadIdx.x * 4; i < 16384; i += 1024) {
    float4 v = *(const float4*)(p + i);
    s += (double)fabsf(v.x) + (double)fabsf(v.y) + (double)fabsf(v.z) + (double)fabsf(v.w);
  }
  __shared__ double red[256];
  red[threadIdx.x] = s;
  __syncthreads();
  for (int off = 128; off > 0; off >>= 1) {
    if ((int)threadIdx.x < off) red[threadIdx.x] += red[threadIdx.x + off];
    __syncthreads();
  }
  if (threadIdx.x == 0) part[m * 256 + blk] = red[0];
}

__global__ void k_wscale_final(const double* __restrict__ part, float* __restrict__ scales) {
  int m = threadIdx.x;
  if (m < 4) {
    double s = 0.0;
    for (int i = 0; i < 256; i++) s += part[m * 256 + i];
    float v = (float)(s * (1.0 / 4194304.0));   // /(D*D), power of 2: exact
    scales[m] = fmaxf(v, 1e-6f);
  }
}

// ---------------- ternary weight quant -> bf16 ------------------------------
__global__ void k_wquant(const float* __restrict__ w0, const float* __restrict__ w1,
                         const float* __restrict__ w2, const float* __restrict__ w3,
                         u16* __restrict__ wq, const float* __restrict__ scales) {
  int m = blockIdx.y;
  const float* w = (m == 0) ? w0 : (m == 1) ? w1 : (m == 2) ? w2 : w3;
  float ws = scales[m];
  size_t i = ((size_t)blockIdx.x * 256 + threadIdx.x) * 4;
  float4 v = *(const float4*)(w + i);
  u16* o = wq + (size_t)m * DD * DD + i;
  float a = fminf(1.f, fmaxf(-1.f, rintf(v.x / ws)));
  float b = fminf(1.f, fmaxf(-1.f, rintf(v.y / ws)));
  float c = fminf(1.f, fmaxf(-1.f, rintf(v.z / ws)));
  float d = fminf(1.f, fmaxf(-1.f, rintf(v.w / ws)));
  ushort4 pk;
  pk.x = f2bf(a); pk.y = f2bf(b); pk.z = f2bf(c); pk.w = f2bf(d);
  *(ushort4*)o = pk;
}

// ---------------- fused per-token absmax + int8-range quant -> bf16 ---------
// One block per row: load 8 f32/thread, reduce max, quantize from registers.
__global__ __launch_bounds__(256) void k_rowquant(const float* __restrict__ x, u16* __restrict__ xq,
                                                  float* __restrict__ amax) {
  int row = blockIdx.x, t = threadIdx.x;
  const float* p = x + (size_t)row * DD + t * 8;
  float4 v0 = *(const float4*)(p);
  float4 v1 = *(const float4*)(p + 4);
  float m = fmaxf(fmaxf(fmaxf(fabsf(v0.x), fabsf(v0.y)), fmaxf(fabsf(v0.z), fabsf(v0.w))),
                  fmaxf(fmaxf(fabsf(v1.x), fabsf(v1.y)), fmaxf(fabsf(v1.z), fabsf(v1.w))));
  m = fmaxf(m, __shfl_xor(m, 1));  m = fmaxf(m, __shfl_xor(m, 2));
  m = fmaxf(m, __shfl_xor(m, 4));  m = fmaxf(m, __shfl_xor(m, 8));
  m = fmaxf(m, __shfl_xor(m, 16)); m = fmaxf(m, __shfl_xor(m, 32));
  __shared__ float red[4];
  if ((t & 63) == 0) red[t >> 6] = m;
  __syncthreads();
  m = fmaxf(fmaxf(red[0], red[1]), fmaxf(red[2], red[3]));
  m = fmaxf(m, 1e-8f);                 // clip(amax, 1e-8)
  if (t == 0) amax[row] = m;
  float s = 127.0f / m;                // matches ref: QMAX / a_max
  u16 o[8];
  o[0] = f2bf(fminf(127.f, fmaxf(-127.f, rintf(v0.x * s))));
  o[1] = f2bf(fminf(127.f, fmaxf(-127.f, rintf(v0.y * s))));
  o[2] = f2bf(fminf(127.f, fmaxf(-127.f, rintf(v0.z * s))));
  o[3] = f2bf(fminf(127.f, fmaxf(-127.f, rintf(v0.w * s))));
  o[4] = f2bf(fminf(127.f, fmaxf(-127.f, rintf(v1.x * s))));
  o[5] = f2bf(fminf(127.f, fmaxf(-127.f, rintf(v1.y * s))));
  o[6] = f2bf(fminf(127.f, fmaxf(-127.f, rintf(v1.z * s))));
  o[7] = f2bf(fminf(127.f, fmaxf(-127.f, rintf(v1.w * s))));
  *(int4*)(xq + (size_t)row * DD + t * 8) = *(const int4*)o;
}

// ---------------- bf16 MFMA GEMM: C[m][n] = sum_k A[m][k]*Bw[n][k] ----------
// Phase-split counted-vmcnt schedule (T2+T3+T4+T5):
//  BM=128 BN=256 BK=64, 8 waves (2M x 4N), per-wave 64x64 (4m x 4n frags).
//  n-frag interleave (wc+4j): phase1 consumes B-half0 only, phase2 B-half1
//  only -> staggered stage windows. Stages: ph1 -> A(t+1)+B1(t+1) (buf t+1),
//  ph2 -> B0(t+2) (cur buf, half0 free after ph1). Checkpoint per K-tile:
//  vmcnt(2) (1 stage in flight), vmcnt(0) only at tail t=30.
//  LDS 96KB double-buffered, 16B-block XOR swizzle (proven 0 conflicts).
template<bool OB, int NBNL>
__global__ __launch_bounds__(512) void k_gemm(const u16* __restrict__ A, const u16* __restrict__ Bw,
                                              const float* __restrict__ amax,
                                              const float* __restrict__ scales, int sbase,
                                              void* __restrict__ outv) {
  __shared__ alignas(16) u16 Asm[2][128 * 64];
  __shared__ alignas(16) u16 Bsm[2][256 * 64];
  int id = blockIdx.x;
  int xcd = id & 7, kk = id >> 3;
  int bm = kk & 31, bn = xcd * NBNL + (kk >> 5);   // bm-inner: B-panel L2-resident per XCD
  int t = threadIdx.x, w = t >> 6, l = t & 63;
  int wr = w >> 2, wc = w & 3;                     // 2M x 4N waves
  int l15 = l & 15, lh = l >> 4;
  int r0 = t >> 3;                                 // staging row (i=0); i=1 row = r0+64
  int c0 = ((t & 7) ^ (r0 & 7)) * 8;               // pre-swizzled source column
  const u16* Ab = A  + (size_t)(bm * 128) * DD;
  const u16* Bb = Bw + (size_t)(bn * 256) * DD;

#define STG_A(tt) do { u16* d_ = &Asm[(tt) & 1][0];                                   \
    gl_lds16(Ab + (size_t)r0 * DD + (tt) * 64 + c0,        d_ + t * 8);               \
    gl_lds16(Ab + (size_t)(r0 + 64) * DD + (tt) * 64 + c0, d_ + (512 + t) * 8); } while (0)
#define STG_B(tt, h_) do { u16* d_ = &Bsm[(tt) & 1][(h_) * 8192];                     \
    gl_lds16(Bb + (size_t)((h_) * 128 + r0) * DD + (tt) * 64 + c0,        d_ + t * 8);\
    gl_lds16(Bb + (size_t)((h_) * 128 + r0 + 64) * DD + (tt) * 64 + c0,   d_ + (512 + t) * 8); } while (0)

  f32x4 acc[4][4] = {};
  // prologue: tile0 complete + B0(1); newest stage (B0(1)) may stay in flight
  STG_A(0); STG_B(0, 0); STG_B(0, 1); STG_B(1, 0);
  asm volatile("s_waitcnt vmcnt(2)" ::: "memory");
  asm volatile("s_barrier" ::: "memory");
  for (int kb = 0; kb < 32; kb++) {
    int b = kb & 1;
    const u16* Ac = &Asm[b][0];
    const u16* Bc = &Bsm[b][0];
    // ---- phase 1: A frags + B frags j=0,1 (B-half0); MFMA quads j<2 ----
    bf16x8 af[4][2], bf[2][2];
    #pragma unroll
    for (int i = 0; i < 4; i++)
      #pragma unroll
      for (int ks = 0; ks < 2; ks++)
        af[i][ks] = *(const bf16x8*)(Ac + (wr * 64 + i * 16 + l15) * 64 + (((ks * 4 + lh) ^ (l15 & 7)) * 8));
    #pragma unroll
    for (int j = 0; j < 2; j++)
      #pragma unroll
      for (int ks = 0; ks < 2; ks++)
        bf[j][ks] = *(const bf16x8*)(Bc + ((wc + 4 * j) * 16 + l15) * 64 + (((ks * 4 + lh) ^ (l15 & 7)) * 8));
    if (kb + 1 < 32) { STG_A(kb + 1); STG_B(kb + 1, 1); }
    asm volatile("s_barrier" ::: "memory");
    asm volatile("s_waitcnt lgkmcnt(0)" ::: "memory");
    __builtin_amdgcn_sched_barrier(0);
    __builtin_amdgcn_s_setprio(1);
    #pragma unroll
    for (int ks = 0; ks < 2; ks++)
      #pragma unroll
      for (int i = 0; i < 4; i++)
        #pragma unroll
        for (int j = 0; j < 2; j++)
          acc[i][j] = MFMA(af[i][ks], bf[j][ks], acc[i][j]);
    __builtin_amdgcn_s_setprio(0);
    asm volatile("s_barrier" ::: "memory");
    // ---- phase 2: B frags j=2,3 (B-half1); MFMA quads j>=2 ----
    bf16x8 bg[2][2];
    #pragma unroll
    for (int j = 0; j < 2; j++)
      #pragma unroll
      for (int ks = 0; ks < 2; ks++)
        bg[j][ks] = *(const bf16x8*)(Bc + ((wc + 4 * (2 + j)) * 16 + l15) * 64 + (((ks * 4 + lh) ^ (l15 & 7)) * 8));
    if (kb + 2 < 32) STG_B(kb + 2, 0);
    asm volatile("s_barrier" ::: "memory");
    asm volatile("s_waitcnt lgkmcnt(0)" ::: "memory");
    __builtin_amdgcn_sched_barrier(0);
    __builtin_amdgcn_s_setprio(1);
    #pragma unroll
    for (int ks = 0; ks < 2; ks++)
      #pragma unroll
      for (int i = 0; i < 4; i++)
        #pragma unroll
        for (int j = 0; j < 2; j++)
          acc[i][2 + j] = MFMA(af[i][ks], bg[j][ks], acc[i][2 + j]);
    __builtin_amdgcn_s_setprio(0);
    // checkpoint: counted vmcnt, collective via barrier (never 0 mid-loop)
    if (kb < 30) {
      asm volatile("s_waitcnt vmcnt(2)" ::: "memory");
      asm volatile("s_barrier" ::: "memory");
    } else if (kb == 30) {
      asm volatile("s_waitcnt vmcnt(0)" ::: "memory");
      asm volatile("s_barrier" ::: "memory");
    }
  }
#undef STG_A
#undef STG_B
  int mz = OB ? (bn >> 3) : 0;
  int lcol0 = OB ? ((bn & 7) * 256) : (bn * 256);
  float wsc = scales[sbase + mz];
  u16*   outb = (u16*)outv + (size_t)mz * MM * DD;
  float* outf = (float*)outv;
  #pragma unroll
  for (int i = 0; i < 4; i++) {
    int row0 = bm * 128 + wr * 64 + i * 16 + lh * 4;
    #pragma unroll
    for (int r = 0; r < 4; r++) {
      float sc = (wsc * amax[row0 + r]) / 127.0f;
      #pragma unroll
      for (int j = 0; j < 4; j++) {
        int col = lcol0 + (wc + 4 * j) * 16 + l15;
        float y = acc[i][j][r] * sc;
        if (OB) outb[(size_t)(row0 + r) * DD + col] = f2bf(y);
        else    outf[(size_t)(row0 + r) * DD + col] = y;
      }
    }
  }
}

// ---------------- V transpose: v[b*S+s][h*128+d] -> vt[(b*16+h)*128+d][s] ---
__global__ __launch_bounds__(256) void k_vtrans(const u16* __restrict__ v, u16* __restrict__ vt) {
  __shared__ u16 tile[64][72];
  int sb = blockIdx.x;           // S/64
  int db = blockIdx.y;           // HD/64
  int bh = blockIdx.z;           // B*H
  int b = bh >> 4, h = bh & 15;
  int t = threadIdx.x;
  int ls = t >> 2, ld0 = (t & 3) * 16;
  const u16* src = v + (size_t)(b * SS + sb * 64 + ls) * DD + h * HDD + db * 64 + ld0;
  *(int4*)(&tile[ls][ld0])     = *(const int4*)(src);
  *(int4*)(&tile[ls][ld0 + 8]) = *(const int4*)(src + 8);
  __syncthreads();
  int d = t >> 2, s0 = (t & 3) * 16;
  u16 tmp[16];
  #pragma unroll
  for (int k = 0; k < 16; k++) tmp[k] = tile[s0 + k][d];
  u16* dst = vt + (size_t)((bh * HDD) + db * 64 + d) * SS + sb * 64 + s0;
  *(int4*)(dst)     = *(const int4*)(tmp);
  *(int4*)(dst + 8) = *(const int4*)(tmp + 8);
}

// ---------------- causal flash attention (FROZEN from round 3) --------------
__global__ __launch_bounds__(256) void k_attn(const u16* __restrict__ Q, const u16* __restrict__ K,
                                              const u16* __restrict__ VT, float* __restrict__ O) {
  __shared__ u16 Ks[64 * 128];   // [s][d]  256B rows, swizzled blocks
  __shared__ u16 Vs[128 * 64];   // [d][s]  128B rows, swizzled blocks
  __shared__ u16 Ps[4 * 16 * 72];
  int id = blockIdx.x;
  int orig = ((id & 7) << 7) | (id >> 3);   // bijective: XCD x -> bh 4x..4x+3
  int qb = orig & 31, bh = orig >> 5;
  int b = bh >> 4, h = bh & 15;
  int t = threadIdx.x, w = t >> 6, l = t & 63;
  int l15 = l & 15, lh = l >> 4;
  size_t base = (size_t)(b * SS) * DD + h * HDD;
  const u16* vtb = VT + (size_t)bh * HDD * SS;
  u16* Pw = Ps + w * 16 * 72;
  bf16x8 qf[4];
  {
    const u16* qp = Q + base + (size_t)(qb * 64 + w * 16 + l15) * DD + lh * 8;
    #pragma unroll
    for (int kt = 0; kt < 4; kt++) qf[kt] = *(const bf16x8*)(qp + kt * 32);
  }
  f32x4 cacc[8] = {};
  float mrun[4], lrun[4];
  #pragma unroll
  for (int r = 0; r < 4; r++) { mrun[r] = -INFINITY; lrun[r] = 0.f; }
  const float sc = 0.08838834764831845f;  // 1/sqrt(128)
  int ksr[4], ksc[4], vsr[4], vsc[4];
  #pragma unroll
  for (int i = 0; i < 4; i++) {
    int s = i * 256 + t;
    ksr[i] = s >> 4; ksc[i] = (((t & 15) ^ (ksr[i] & 7)) * 8);
    vsr[i] = s >> 3; vsc[i] = (((t & 7)  ^ (vsr[i] & 7)) * 8);
  }
  for (int kb = 0; kb <= qb; kb++) {
    #pragma unroll
    for (int i = 0; i < 4; i++) {
      gl_lds16(K + base + (size_t)(kb * 64 + ksr[i]) * DD + ksc[i], Ks + (size_t)(i * 256 + t) * 8);
      gl_lds16(vtb + (size_t)vsr[i] * SS + kb * 64 + vsc[i],        Vs + (size_t)(i * 256 + t) * 8);
    }
    __syncthreads();
    f32x4 sf[4] = {};
    #pragma unroll
    for (int nt = 0; nt < 4; nt++) {
      #pragma unroll
      for (int kt = 0; kt < 4; kt++) {
        bf16x8 kf = *(const bf16x8*)(Ks + (nt * 16 + l15) * 128 + (((kt * 4 + lh) ^ (l15 & 7)) * 8));
        sf[nt] = MFMA(qf[kt], kf, sf[nt]);
      }
    }
    bool diag = (kb == qb);
    #pragma unroll
    for (int nt = 0; nt < 4; nt++) {
      #pragma unroll
      for (int r = 0; r < 4; r++) {
        float v = sf[nt][r] * sc;
        if (diag && (nt * 16 + l15) > (w * 16 + lh * 4 + r)) v = -1e30f;
        sf[nt][r] = v;
      }
    }
    #pragma unroll
    for (int r = 0; r < 4; r++) {
      float mx = fmaxf(fmaxf(sf[0][r], sf[1][r]), fmaxf(sf[2][r], sf[3][r]));
      mx = fmaxf(mx, __shfl_xor(mx, 1)); mx = fmaxf(mx, __shfl_xor(mx, 2));
      mx = fmaxf(mx, __shfl_xor(mx, 4)); mx = fmaxf(mx, __shfl_xor(mx, 8));
      float mnew = fmaxf(mrun[r], mx);
      float alpha = __expf(mrun[r] - mnew);
      float s0 = 0.f;
      #pragma unroll
      for (int nt = 0; nt < 4; nt++) { float pv = __expf(sf[nt][r] - mnew); sf[nt][r] = pv; s0 += pv; }
      s0 += __shfl_xor(s0, 1); s0 += __shfl_xor(s0, 2);
      s0 += __shfl_xor(s0, 4); s0 += __shfl_xor(s0, 8);
      lrun[r] = lrun[r] * alpha + s0;
      mrun[r] = mnew;
      #pragma unroll
      for (int n2 = 0; n2 < 8; n2++) cacc[n2][r] *= alpha;
    }
    #pragma unroll
    for (int r = 0; r < 4; r++)
      #pragma unroll
      for (int nt = 0; nt < 4; nt++)
        Pw[(lh * 4 + r) * 72 + nt * 16 + l15] = f2bf(sf[nt][r]);
    #pragma unroll
    for (int ks = 0; ks < 2; ks++) {
      bf16x8 pf = *(const bf16x8*)(Pw + l15 * 72 + ks * 32 + lh * 8);
      #pragma unroll
      for (int n2 = 0; n2 < 8; n2++) {
        bf16x8 vf = *(const bf16x8*)(Vs + (n2 * 16 + l15) * 64 + (((ks * 4 + lh) ^ (l15 & 7)) * 8));
        cacc[n2] = MFMA(pf, vf, cacc[n2]);
      }
    }
    __syncthreads();
  }
  #pragma unroll
  for (int r = 0; r < 4; r++) {
    float inv = 1.0f / lrun[r];
    float* op = O + base + (size_t)(qb * 64 + w * 16 + lh * 4 + r) * DD;
    #pragma unroll
    for (int n2 = 0; n2 < 8; n2++) op[n2 * 16 + l15] = cacc[n2][r] * inv;
  }
}

// ---------------- launch ----------------------------------------------------
// ws layout (bytes), total ~134.4 MB:
//   0        scales (4 f32)        256      partials (1024 f64)
//   16384    amax_x                49152    amax_ctx
//   131072   w_q bf16 (4 x D*D)  = 33,554,432
//   33685504 x_q bf16 (M*D)      = 16,777,216   (reused as V^T, then ctx_q)
//   50462720 q bf16 | 67239936 k | 84017152 v   (16,777,216 each, contiguous)
//   100794368 ctx f32            = 33,554,432
extern "C" void kernel_launch(void* const* d_in, const int* in_sizes, int n_in,
                              void* d_out, int out_size, void* d_ws, size_t ws_size,
                              hipStream_t stream) {
  const float* x  = (const float*)d_in[0];
  const float* wq = (const float*)d_in[1];
  const float* wk = (const float*)d_in[2];
  const float* wv = (const float*)d_in[3];
  const float* wo = (const float*)d_in[4];
  char* ws = (char*)d_ws;
  float*  scales = (float*)(ws + 0);
  double* part   = (double*)(ws + 256);
  float*  amaxx  = (float*)(ws + 16384);
  float*  amaxc  = (float*)(ws + 49152);
  u16*    wqq    = (u16*)(ws + 131072);
  u16*    xq     = (u16*)(ws + 33685504);   // reused as V^T, then ctx_q
  u16*    qb     = (u16*)(ws + 50462720);
  u16*    kb     = (u16*)(ws + 67239936);
  u16*    vb     = (u16*)(ws + 84017152);
  float*  ctx    = (float*)(ws + 100794368);
  (void)in_sizes; (void)n_in; (void)out_size; (void)ws_size;

  k_wabs_partial<<<1024, 256, 0, stream>>>(wq, wk, wv, wo, part);
  k_wscale_final<<<1, 64, 0, stream>>>(part, scales);
  k_wquant<<<dim3(4096, 4), 256, 0, stream>>>(wq, wk, wv, wo, wqq, scales);
  k_rowquant<<<MM, 256, 0, stream>>>(x, xq, amaxx);
  // fused QKV projection: M=4096 x N=6144 over stacked Wq/Wk/Wv; q/k/v
  // outputs contiguous so mz picks the buffer. 768 blocks = exactly 3/CU.
  k_gemm<true, 3><<<768, 512, 0, stream>>>(xq, wqq, amaxx, scales, 0, (void*)qb);
  // V^T into the (now dead) xq region; then LDS-staged flash attention
  k_vtrans<<<dim3(32, 2, 32), 256, 0, stream>>>(vb, xq);
  k_attn<<<1024, 256, 0, stream>>>(qb, kb, xq, ctx);
  k_rowquant<<<MM, 256, 0, stream>>>(ctx, xq, amaxc);   // ctx_q overwrites V^T
  // WO projection: 256 blocks = exactly 1/CU; per-XCD B-panel resident.
  k_gemm<false, 1><<<256, 512, 0, stream>>>(xq, wqq + (size_t)3 * DD * DD, amaxc, scales, 3, d_out);
}

// Round 7
// 293.192 us; speedup vs baseline: 1.2833x; 1.1185x over previous
//
#include <hip/hip_runtime.h>
#include <hip/hip_bf16.h>
#include <cstdint>
#include <cstddef>

// BitNet b1.58 attention block: B=2 S=2048 D=2048 H=16 HD=128.
// All quantized matmuls done in bf16 MFMA (exact: int8 x ternary, sums < 2^24).

#define BB 2
#define SS 2048
#define DD 2048
#define HH 16
#define HDD 128
#define MM (BB*SS)   // 4096 token rows

typedef __attribute__((ext_vector_type(8))) short bf16x8;
typedef __attribute__((ext_vector_type(4))) float f32x4;
typedef __attribute__((ext_vector_type(16))) float f32x16;
typedef unsigned short u16;
typedef unsigned int   u32;

#define MFMA(a,b,c)   __builtin_amdgcn_mfma_f32_16x16x32_bf16(a,b,c,0,0,0)
#define MFMA32(a,b,c) __builtin_amdgcn_mfma_f32_32x32x16_bf16(a,b,c,0,0,0)

static __device__ __forceinline__ u16 f2bf(float f) {
  // round-to-nearest-even float->bf16 (no NaN inputs here)
  u32 x = __float_as_uint(f);
  u32 r = x + 0x7fffu + ((x >> 16) & 1u);
  return (u16)(r >> 16);
}

// async global->LDS, 16B per lane; LDS dest must be linear (base + lane*16)
static __device__ __forceinline__ void gl_lds16(const u16* g, u16* l) {
  __builtin_amdgcn_global_load_lds((const __attribute__((address_space(1))) void*)g,
                                   (__attribute__((address_space(3))) void*)l, 16, 0, 0);
}

// ---------------- weight scale: deterministic two-stage |w| mean in f64 ----
__global__ void k_wabs_partial(const float* __restrict__ w0, const float* __restrict__ w1,
                               const float* __restrict__ w2, const float* __restrict__ w3,
                               double* __restrict__ part) {
  int m = blockIdx.x >> 8, blk = blockIdx.x & 255;
  const float* w = (m == 0) ? w0 : (m == 1) ? w1 : (m == 2) ? w2 : w3;
  const float* p = w + (size_t)blk * 16384;
  double s = 0.0;
  for (int i = threadIdx.x * 4; i < 16384; i += 1024) {
    float4 v = *(const float4*)(p + i);
    s += (double)fabsf(v.x) + (double)fabsf(v.y) + (double)fabsf(v.z) + (double)fabsf(v.w);
  }
  __shared__ double red[256];
  red[threadIdx.x] = s;
  __syncthreads();
  for (int off = 128; off > 0; off >>= 1) {
    if ((int)threadIdx.x < off) red[threadIdx.x] += red[threadIdx.x + off];
    __syncthreads();
  }
  if (threadIdx.x == 0) part[m * 256 + blk] = red[0];
}

__global__ void k_wscale_final(const double* __restrict__ part, float* __restrict__ scales) {
  int m = threadIdx.x;
  if (m < 4) {
    double s = 0.0;
    for (int i = 0; i < 256; i++) s += part[m * 256 + i];
    float v = (float)(s * (1.0 / 4194304.0));   // /(D*D), power of 2: exact
    scales[m] = fmaxf(v, 1e-6f);
  }
}

// ---------------- ternary weight quant -> bf16 ------------------------------
__global__ void k_wquant(const float* __restrict__ w0, const float* __restrict__ w1,
                         const float* __restrict__ w2, const float* __restrict__ w3,
                         u16* __restrict__ wq, const float* __restrict__ scales) {
  int m = blockIdx.y;
  const float* w = (m == 0) ? w0 : (m == 1) ? w1 : (m == 2) ? w2 : w3;
  float ws = scales[m];
  size_t i = ((size_t)blockIdx.x * 256 + threadIdx.x) * 4;
  float4 v = *(const float4*)(w + i);
  u16* o = wq + (size_t)m * DD * DD + i;
  float a = fminf(1.f, fmaxf(-1.f, rintf(v.x / ws)));
  float b = fminf(1.f, fmaxf(-1.f, rintf(v.y / ws)));
  float c = fminf(1.f, fmaxf(-1.f, rintf(v.z / ws)));
  float d = fminf(1.f, fmaxf(-1.f, rintf(v.w / ws)));
  ushort4 pk;
  pk.x = f2bf(a); pk.y = f2bf(b); pk.z = f2bf(c); pk.w = f2bf(d);
  *(ushort4*)o = pk;
}

// ---------------- fused per-token absmax + int8-range quant -> bf16 ---------
__global__ __launch_bounds__(256) void k_rowquant(const float* __restrict__ x, u16* __restrict__ xq,
                                                  float* __restrict__ amax) {
  int row = blockIdx.x, t = threadIdx.x;
  const float* p = x + (size_t)row * DD + t * 8;
  float4 v0 = *(const float4*)(p);
  float4 v1 = *(const float4*)(p + 4);
  float m = fmaxf(fmaxf(fmaxf(fabsf(v0.x), fabsf(v0.y)), fmaxf(fabsf(v0.z), fabsf(v0.w))),
                  fmaxf(fmaxf(fabsf(v1.x), fabsf(v1.y)), fmaxf(fabsf(v1.z), fabsf(v1.w))));
  m = fmaxf(m, __shfl_xor(m, 1));  m = fmaxf(m, __shfl_xor(m, 2));
  m = fmaxf(m, __shfl_xor(m, 4));  m = fmaxf(m, __shfl_xor(m, 8));
  m = fmaxf(m, __shfl_xor(m, 16)); m = fmaxf(m, __shfl_xor(m, 32));
  __shared__ float red[4];
  if ((t & 63) == 0) red[t >> 6] = m;
  __syncthreads();
  m = fmaxf(fmaxf(red[0], red[1]), fmaxf(red[2], red[3]));
  m = fmaxf(m, 1e-8f);                 // clip(amax, 1e-8)
  if (t == 0) amax[row] = m;
  float s = 127.0f / m;                // matches ref: QMAX / a_max
  u16 o[8];
  o[0] = f2bf(fminf(127.f, fmaxf(-127.f, rintf(v0.x * s))));
  o[1] = f2bf(fminf(127.f, fmaxf(-127.f, rintf(v0.y * s))));
  o[2] = f2bf(fminf(127.f, fmaxf(-127.f, rintf(v0.z * s))));
  o[3] = f2bf(fminf(127.f, fmaxf(-127.f, rintf(v0.w * s))));
  o[4] = f2bf(fminf(127.f, fmaxf(-127.f, rintf(v1.x * s))));
  o[5] = f2bf(fminf(127.f, fmaxf(-127.f, rintf(v1.y * s))));
  o[6] = f2bf(fminf(127.f, fmaxf(-127.f, rintf(v1.z * s))));
  o[7] = f2bf(fminf(127.f, fmaxf(-127.f, rintf(v1.w * s))));
  *(int4*)(xq + (size_t)row * DD + t * 8) = *(const int4*)o;
}

// ---------------- bf16 MFMA GEMM (FROZEN from round 5) ----------------------
template<bool OB, int NBNL>
__global__ __launch_bounds__(512) void k_gemm(const u16* __restrict__ A, const u16* __restrict__ Bw,
                                              const float* __restrict__ amax,
                                              const float* __restrict__ scales, int sbase,
                                              void* __restrict__ outv) {
  __shared__ alignas(16) u16 Asm[2][128 * 64];
  __shared__ alignas(16) u16 Bsm[2][256 * 64];
  int id = blockIdx.x;
  int xcd = id & 7, kk = id >> 3;
  int bm = kk & 31, bn = xcd * NBNL + (kk >> 5);   // bm-inner: B-panel L2-resident per XCD
  int t = threadIdx.x, w = t >> 6, l = t & 63;
  int wr = w >> 2, wc = w & 3;                     // 2M x 4N waves
  int l15 = l & 15, lh = l >> 4;
  int r0 = t >> 3;                                 // staging row (i=0); i=1 row = r0+64
  int c0 = ((t & 7) ^ (r0 & 7)) * 8;               // pre-swizzled source column
  const u16* Ab = A  + (size_t)(bm * 128) * DD;
  const u16* Bb = Bw + (size_t)(bn * 256) * DD;

#define STG_A(tt) do { u16* d_ = &Asm[(tt) & 1][0];                                   \
    gl_lds16(Ab + (size_t)r0 * DD + (tt) * 64 + c0,        d_ + t * 8);               \
    gl_lds16(Ab + (size_t)(r0 + 64) * DD + (tt) * 64 + c0, d_ + (512 + t) * 8); } while (0)
#define STG_B(tt, h_) do { u16* d_ = &Bsm[(tt) & 1][(h_) * 8192];                     \
    gl_lds16(Bb + (size_t)((h_) * 128 + r0) * DD + (tt) * 64 + c0,        d_ + t * 8);\
    gl_lds16(Bb + (size_t)((h_) * 128 + r0 + 64) * DD + (tt) * 64 + c0,   d_ + (512 + t) * 8); } while (0)

  f32x4 acc[4][4] = {};
  STG_A(0); STG_B(0, 0); STG_B(0, 1); STG_B(1, 0);
  asm volatile("s_waitcnt vmcnt(2)" ::: "memory");
  asm volatile("s_barrier" ::: "memory");
  for (int kb = 0; kb < 32; kb++) {
    int b = kb & 1;
    const u16* Ac = &Asm[b][0];
    const u16* Bc = &Bsm[b][0];
    bf16x8 af[4][2], bf[2][2];
    #pragma unroll
    for (int i = 0; i < 4; i++)
      #pragma unroll
      for (int ks = 0; ks < 2; ks++)
        af[i][ks] = *(const bf16x8*)(Ac + (wr * 64 + i * 16 + l15) * 64 + (((ks * 4 + lh) ^ (l15 & 7)) * 8));
    #pragma unroll
    for (int j = 0; j < 2; j++)
      #pragma unroll
      for (int ks = 0; ks < 2; ks++)
        bf[j][ks] = *(const bf16x8*)(Bc + ((wc + 4 * j) * 16 + l15) * 64 + (((ks * 4 + lh) ^ (l15 & 7)) * 8));
    if (kb + 1 < 32) { STG_A(kb + 1); STG_B(kb + 1, 1); }
    asm volatile("s_barrier" ::: "memory");
    asm volatile("s_waitcnt lgkmcnt(0)" ::: "memory");
    __builtin_amdgcn_sched_barrier(0);
    __builtin_amdgcn_s_setprio(1);
    #pragma unroll
    for (int ks = 0; ks < 2; ks++)
      #pragma unroll
      for (int i = 0; i < 4; i++)
        #pragma unroll
        for (int j = 0; j < 2; j++)
          acc[i][j] = MFMA(af[i][ks], bf[j][ks], acc[i][j]);
    __builtin_amdgcn_s_setprio(0);
    asm volatile("s_barrier" ::: "memory");
    bf16x8 bg[2][2];
    #pragma unroll
    for (int j = 0; j < 2; j++)
      #pragma unroll
      for (int ks = 0; ks < 2; ks++)
        bg[j][ks] = *(const bf16x8*)(Bc + ((wc + 4 * (2 + j)) * 16 + l15) * 64 + (((ks * 4 + lh) ^ (l15 & 7)) * 8));
    if (kb + 2 < 32) STG_B(kb + 2, 0);
    asm volatile("s_barrier" ::: "memory");
    asm volatile("s_waitcnt lgkmcnt(0)" ::: "memory");
    __builtin_amdgcn_sched_barrier(0);
    __builtin_amdgcn_s_setprio(1);
    #pragma unroll
    for (int ks = 0; ks < 2; ks++)
      #pragma unroll
      for (int i = 0; i < 4; i++)
        #pragma unroll
        for (int j = 0; j < 2; j++)
          acc[i][2 + j] = MFMA(af[i][ks], bg[j][ks], acc[i][2 + j]);
    __builtin_amdgcn_s_setprio(0);
    if (kb < 30) {
      asm volatile("s_waitcnt vmcnt(2)" ::: "memory");
      asm volatile("s_barrier" ::: "memory");
    } else if (kb == 30) {
      asm volatile("s_waitcnt vmcnt(0)" ::: "memory");
      asm volatile("s_barrier" ::: "memory");
    }
  }
#undef STG_A
#undef STG_B
  int mz = OB ? (bn >> 3) : 0;
  int lcol0 = OB ? ((bn & 7) * 256) : (bn * 256);
  float wsc = scales[sbase + mz];
  u16*   outb = (u16*)outv + (size_t)mz * MM * DD;
  float* outf = (float*)outv;
  #pragma unroll
  for (int i = 0; i < 4; i++) {
    int row0 = bm * 128 + wr * 64 + i * 16 + lh * 4;
    #pragma unroll
    for (int r = 0; r < 4; r++) {
      float sc = (wsc * amax[row0 + r]) / 127.0f;
      #pragma unroll
      for (int j = 0; j < 4; j++) {
        int col = lcol0 + (wc + 4 * j) * 16 + l15;
        float y = acc[i][j][r] * sc;
        if (OB) outb[(size_t)(row0 + r) * DD + col] = f2bf(y);
        else    outf[(size_t)(row0 + r) * DD + col] = y;
      }
    }
  }
}

// ---------------- V transpose: v[b*S+s][h*128+d] -> vt[(b*16+h)*128+d][s] ---
__global__ __launch_bounds__(256) void k_vtrans(const u16* __restrict__ v, u16* __restrict__ vt) {
  __shared__ u16 tile[64][72];
  int sb = blockIdx.x;           // S/64
  int db = blockIdx.y;           // HD/64
  int bh = blockIdx.z;           // B*H
  int b = bh >> 4, h = bh & 15;
  int t = threadIdx.x;
  int ls = t >> 2, ld0 = (t & 3) * 16;
  const u16* src = v + (size_t)(b * SS + sb * 64 + ls) * DD + h * HDD + db * 64 + ld0;
  *(int4*)(&tile[ls][ld0])     = *(const int4*)(src);
  *(int4*)(&tile[ls][ld0 + 8]) = *(const int4*)(src + 8);
  __syncthreads();
  int d = t >> 2, s0 = (t & 3) * 16;
  u16 tmp[16];
  #pragma unroll
  for (int k = 0; k < 16; k++) tmp[k] = tile[s0 + k][d];
  u16* dst = vt + (size_t)((bh * HDD) + db * 64 + d) * SS + sb * 64 + s0;
  *(int4*)(dst)     = *(const int4*)(tmp);
  *(int4*)(dst + 8) = *(const int4*)(tmp + 8);
}

// ---------------- causal flash attention (hybrid) ---------------------------
// 2 warps x 32 q-rows (QBLK=64), KVBLK=64.
// QK^T: 32x32 swapped (S^T = K.Q^T) -> lane owns one q-row (D col = lane&31);
// softmax fully in-register (trees + ONE shfl_xor(32)), defer-max THR=8.
// P -> per-warp LDS (coalesced b64 writes, XOR-slot swizzle), then the
// round-5-VERIFIED 16x16x32 PV path (A=P rows, B=V^T rows from Vs).
// Per-row alpha/inv broadcast to the 16x16 accum layout via 8 indep __shfl.
// Causal balance: q-tiles (qt, 31-qt) paired -> every block 33 K-tiles.
__global__ __launch_bounds__(128) void k_attn(const u16* __restrict__ Q, const u16* __restrict__ K,
                                              const u16* __restrict__ VT, float* __restrict__ O) {
  __shared__ u16 Ks[64 * 128];   // [kv][d]  256B rows, 16B slots XOR (row&15)
  __shared__ u16 Vs[128 * 64];   // [d][kv]  128B rows, 16B slots XOR (row&7)
  __shared__ u16 Ps[2 * 32 * 64]; // per-warp P[q][kv], 16B slots XOR (row&7)
  int id = blockIdx.x;
  int xcd = id & 7, rr = id >> 3;
  int bh = xcd * 4 + (rr & 3), pr = rr >> 2;       // pr = 0..15 (pair index)
  int b = bh >> 4, h = bh & 15;
  int t = threadIdx.x, w = t >> 6, l = t & 63;
  int l31 = l & 31, hi = l >> 5;
  int l15 = l & 15, lh = l >> 4;                   // 16x16 roles (PV)
  size_t base = (size_t)(b * SS) * DD + h * HDD;
  const u16* vtb = VT + (size_t)bh * HDD * SS;
  u16* Ptw = Ps + w * 2048;
  const float sc = 0.08838834764831845f;           // 1/sqrt(128)
  // staging slots (K: 16 slots/row XOR row&15; VT: 8 slots/row XOR row&7)
  int ksr[8], kso[8], vsr[8], vso[8];
  #pragma unroll
  for (int i = 0; i < 8; i++) {
    int s = i * 128 + t;
    ksr[i] = s >> 4; kso[i] = ((s & 15) ^ (ksr[i] & 15)) * 8;
    vsr[i] = s >> 3; vso[i] = ((s & 7) ^ (vsr[i] & 7)) * 8;
  }
  for (int half = 0; half < 2; half++) {
    int qt = half ? (31 - pr) : pr;
    int qrow = qt * 64 + w * 32 + l31;
    bf16x8 qf[8];
    #pragma unroll
    for (int kt = 0; kt < 8; kt++)
      qf[kt] = *(const bf16x8*)(Q + base + (size_t)qrow * DD + kt * 16 + hi * 8);
    f32x4 cacc[2][8] = {};
    float mrun = -INFINITY, lrun = 0.f;
    for (int kb = 0; kb <= qt; kb++) {
      #pragma unroll
      for (int i = 0; i < 8; i++)
        gl_lds16(K + base + (size_t)(kb * 64 + ksr[i]) * DD + kso[i], Ks + (i * 128 + t) * 8);
      #pragma unroll
      for (int i = 0; i < 8; i++)
        gl_lds16(vtb + (size_t)vsr[i] * SS + kb * 64 + vso[i], Vs + (i * 128 + t) * 8);
      __syncthreads();
      // ---- S^T = K.Q^T : lane owns q-row (col=l31); kv via regs & hi ----
      f32x16 c0 = {}, c1 = {};
      #pragma unroll
      for (int kt = 0; kt < 8; kt++) {
        int sl = (((kt * 2 + hi) ^ (l31 & 15)) * 8);
        bf16x8 kf0 = *(const bf16x8*)(Ks + l31 * 128 + sl);
        bf16x8 kf1 = *(const bf16x8*)(Ks + (32 + l31) * 128 + sl);
        c0 = MFMA32(kf0, qf[kt], c0);
        c1 = MFMA32(kf1, qf[kt], c1);
      }
      if (kb == qt) {   // causal mask, diagonal tile only
        #pragma unroll
        for (int rg = 0; rg < 16; rg++) {
          int kv0 = kb * 64 + (rg & 3) + 8 * (rg >> 2) + 4 * hi;
          if (kv0 > qrow)      c0[rg] = -1e30f;
          if (kv0 + 32 > qrow) c1[rg] = -1e30f;
        }
      }
      // ---- in-register online softmax (raw S units; sc folded into exp) ----
      float ta[16];
      #pragma unroll
      for (int rg = 0; rg < 16; rg++) ta[rg] = fmaxf(c0[rg], c1[rg]);
      #pragma unroll
      for (int off = 8; off > 0; off >>= 1)
        #pragma unroll
        for (int rg = 0; rg < 8; rg++)
          if (rg < off) ta[rg] = fmaxf(ta[rg], ta[rg + off]);
      float pmax = fmaxf(ta[0], __shfl_xor(ta[0], 32));
      if (__any(pmax - mrun > 90.50967f)) {        // defer-max THR=8 (exp units)
        float mnew = fmaxf(mrun, pmax);
        float alpha = __expf((mrun - mnew) * sc);
        lrun *= alpha;
        #pragma unroll
        for (int m16 = 0; m16 < 2; m16++)
          #pragma unroll
          for (int r = 0; r < 4; r++) {
            float ar = __shfl(alpha, m16 * 16 + lh * 4 + r);
            #pragma unroll
            for (int n2 = 0; n2 < 8; n2++) cacc[m16][n2][r] *= ar;
          }
        mrun = mnew;
      }
      float msc = mrun * sc;
      float ts[16];
      #pragma unroll
      for (int rg = 0; rg < 16; rg++) {
        float p0 = __expf(fmaf(c0[rg], sc, -msc)); c0[rg] = p0;
        float p1 = __expf(fmaf(c1[rg], sc, -msc)); c1[rg] = p1;
        ts[rg] = p0 + p1;
      }
      #pragma unroll
      for (int off = 8; off > 0; off >>= 1)
        #pragma unroll
        for (int rg = 0; rg < 8; rg++)
          if (rg < off) ts[rg] += ts[rg + off];
      lrun += ts[0] + __shfl_xor(ts[0], 32);
      // ---- P -> per-warp LDS: regs (4q4..4q4+3) = kv 8*q4+4*hi+(0..3) ----
      #pragma unroll
      for (int q4 = 0; q4 < 4; q4++) {
        uint2 pk0, pk1;
        pk0.x = (u32)f2bf(c0[4 * q4 + 0]) | ((u32)f2bf(c0[4 * q4 + 1]) << 16);
        pk0.y = (u32)f2bf(c0[4 * q4 + 2]) | ((u32)f2bf(c0[4 * q4 + 3]) << 16);
        pk1.x = (u32)f2bf(c1[4 * q4 + 0]) | ((u32)f2bf(c1[4 * q4 + 1]) << 16);
        pk1.y = (u32)f2bf(c1[4 * q4 + 2]) | ((u32)f2bf(c1[4 * q4 + 3]) << 16);
        *(uint2*)(Ptw + l31 * 64 + ((q4 ^ (l31 & 7)) * 8 + 4 * hi))       = pk0;
        *(uint2*)(Ptw + l31 * 64 + (((4 + q4) ^ (l31 & 7)) * 8 + 4 * hi)) = pk1;
      }
      // ---- PV (round-5-verified 16x16x32 path): O[q][d] += P.V ----
      #pragma unroll
      for (int ks = 0; ks < 2; ks++) {
        int so = ((ks * 4 + lh) ^ (l15 & 7)) * 8;
        bf16x8 pf0 = *(const bf16x8*)(Ptw + (l15) * 64 + so);
        bf16x8 pf1 = *(const bf16x8*)(Ptw + (16 + l15) * 64 + so);
        #pragma unroll
        for (int n2 = 0; n2 < 8; n2++) {
          bf16x8 vf = *(const bf16x8*)(Vs + (n2 * 16 + l15) * 64 + so);
          cacc[0][n2] = MFMA(pf0, vf, cacc[0][n2]);
          cacc[1][n2] = MFMA(pf1, vf, cacc[1][n2]);
        }
      }
      __syncthreads();
    }
    // ---- epilogue: rows = m16*16 + lh*4 + r (within warp), cols = n2*16+l15
    float inv = 1.0f / lrun;
    #pragma unroll
    for (int m16 = 0; m16 < 2; m16++)
      #pragma unroll
      for (int r = 0; r < 4; r++) {
        float ir = __shfl(inv, m16 * 16 + lh * 4 + r);
        float* op = O + base + (size_t)(qt * 64 + w * 32 + m16 * 16 + lh * 4 + r) * DD;
        #pragma unroll
        for (int n2 = 0; n2 < 8; n2++)
          op[n2 * 16 + l15] = cacc[m16][n2][r] * ir;
      }
  }
}

// ---------------- launch ----------------------------------------------------
// ws layout (bytes), total ~134.4 MB:
//   0        scales (4 f32)        256      partials (1024 f64)
//   16384    amax_x                49152    amax_ctx
//   131072   w_q bf16 (4 x D*D)  = 33,554,432
//   33685504 x_q bf16 (M*D)      = 16,777,216   (reused as V^T, then ctx_q)
//   50462720 q bf16 | 67239936 k | 84017152 v   (16,777,216 each, contiguous)
//   100794368 ctx f32            = 33,554,432
extern "C" void kernel_launch(void* const* d_in, const int* in_sizes, int n_in,
                              void* d_out, int out_size, void* d_ws, size_t ws_size,
                              hipStream_t stream) {
  const float* x  = (const float*)d_in[0];
  const float* wq = (const float*)d_in[1];
  const float* wk = (const float*)d_in[2];
  const float* wv = (const float*)d_in[3];
  const float* wo = (const float*)d_in[4];
  char* ws = (char*)d_ws;
  float*  scales = (float*)(ws + 0);
  double* part   = (double*)(ws + 256);
  float*  amaxx  = (float*)(ws + 16384);
  float*  amaxc  = (float*)(ws + 49152);
  u16*    wqq    = (u16*)(ws + 131072);
  u16*    xq     = (u16*)(ws + 33685504);   // reused as V^T, then ctx_q
  u16*    qb     = (u16*)(ws + 50462720);
  u16*    kb     = (u16*)(ws + 67239936);
  u16*    vb     = (u16*)(ws + 84017152);
  float*  ctx    = (float*)(ws + 100794368);
  (void)in_sizes; (void)n_in; (void)out_size; (void)ws_size;

  k_wabs_partial<<<1024, 256, 0, stream>>>(wq, wk, wv, wo, part);
  k_wscale_final<<<1, 64, 0, stream>>>(part, scales);
  k_wquant<<<dim3(4096, 4), 256, 0, stream>>>(wq, wk, wv, wo, wqq, scales);
  k_rowquant<<<MM, 256, 0, stream>>>(x, xq, amaxx);
  k_gemm<true, 3><<<768, 512, 0, stream>>>(xq, wqq, amaxx, scales, 0, (void*)qb);
  k_vtrans<<<dim3(32, 2, 32), 256, 0, stream>>>(vb, xq);
  k_attn<<<512, 128, 0, stream>>>(qb, kb, xq, ctx);
  k_rowquant<<<MM, 256, 0, stream>>>(ctx, xq, amaxc);   // ctx_q overwrites V^T
  k_gemm<false, 1><<<256, 512, 0, stream>>>(xq, wqq + (size_t)3 * DD * DD, amaxc, scales, 3, d_out);
}

// Round 8
// 231.603 us; speedup vs baseline: 1.6245x; 1.2659x over previous
//
#include <hip/hip_runtime.h>
#include <hip/hip_bf16.h>
#include <cstdint>
#include <cstddef>

// BitNet b1.58 attention block: B=2 S=2048 D=2048 H=16 HD=128.
// Projections via int8 MFMA (exact: int8 x ternary, |acc| <= 2048*127 < 2^24);
// attention via bf16 MFMA.

#define BB 2
#define SS 2048
#define DD 2048
#define HH 16
#define HDD 128
#define MM (BB*SS)   // 4096 token rows

typedef __attribute__((ext_vector_type(8))) short bf16x8;
typedef __attribute__((ext_vector_type(4))) float f32x4;
typedef __attribute__((ext_vector_type(16))) float f32x16;
typedef __attribute__((ext_vector_type(4))) int   i32x4;
typedef unsigned short u16;
typedef unsigned int   u32;
typedef unsigned char  u8;
typedef signed char    s8;

#define MFMA(a,b,c)   __builtin_amdgcn_mfma_f32_16x16x32_bf16(a,b,c,0,0,0)
#define MFMA32(a,b,c) __builtin_amdgcn_mfma_f32_32x32x16_bf16(a,b,c,0,0,0)
#define MFMAI8(a,b,c) __builtin_amdgcn_mfma_i32_16x16x64_i8(a,b,c,0,0,0)

static __device__ __forceinline__ u16 f2bf(float f) {
  // round-to-nearest-even float->bf16 (no NaN inputs here)
  u32 x = __float_as_uint(f);
  u32 r = x + 0x7fffu + ((x >> 16) & 1u);
  return (u16)(r >> 16);
}

// async global->LDS, 16B per lane; LDS dest must be linear (base + lane*16)
static __device__ __forceinline__ void gl_lds16(const void* g, void* l) {
  __builtin_amdgcn_global_load_lds((const __attribute__((address_space(1))) void*)g,
                                   (__attribute__((address_space(3))) void*)l, 16, 0, 0);
}

// ---------------- weight scale: deterministic two-stage |w| mean in f64 ----
__global__ void k_wabs_partial(const float* __restrict__ w0, const float* __restrict__ w1,
                               const float* __restrict__ w2, const float* __restrict__ w3,
                               double* __restrict__ part) {
  int m = blockIdx.x >> 8, blk = blockIdx.x & 255;
  const float* w = (m == 0) ? w0 : (m == 1) ? w1 : (m == 2) ? w2 : w3;
  const float* p = w + (size_t)blk * 16384;
  double s = 0.0;
  for (int i = threadIdx.x * 4; i < 16384; i += 1024) {
    float4 v = *(const float4*)(p + i);
    s += (double)fabsf(v.x) + (double)fabsf(v.y) + (double)fabsf(v.z) + (double)fabsf(v.w);
  }
  __shared__ double red[256];
  red[threadIdx.x] = s;
  __syncthreads();
  for (int off = 128; off > 0; off >>= 1) {
    if ((int)threadIdx.x < off) red[threadIdx.x] += red[threadIdx.x + off];
    __syncthreads();
  }
  if (threadIdx.x == 0) part[m * 256 + blk] = red[0];
}

__global__ void k_wscale_final(const double* __restrict__ part, float* __restrict__ scales) {
  int m = threadIdx.x;
  if (m < 4) {
    double s = 0.0;
    for (int i = 0; i < 256; i++) s += part[m * 256 + i];
    float v = (float)(s * (1.0 / 4194304.0));   // /(D*D), power of 2: exact
    scales[m] = fmaxf(v, 1e-6f);
  }
}

// ---------------- ternary weight quant -> int8 ------------------------------
__global__ void k_wquant(const float* __restrict__ w0, const float* __restrict__ w1,
                         const float* __restrict__ w2, const float* __restrict__ w3,
                         s8* __restrict__ wq, const float* __restrict__ scales) {
  int m = blockIdx.y;
  const float* w = (m == 0) ? w0 : (m == 1) ? w1 : (m == 2) ? w2 : w3;
  float ws = scales[m];
  size_t i = ((size_t)blockIdx.x * 256 + threadIdx.x) * 4;
  float4 v = *(const float4*)(w + i);
  s8 o[4];
  o[0] = (s8)(int)fminf(1.f, fmaxf(-1.f, rintf(v.x / ws)));
  o[1] = (s8)(int)fminf(1.f, fmaxf(-1.f, rintf(v.y / ws)));
  o[2] = (s8)(int)fminf(1.f, fmaxf(-1.f, rintf(v.z / ws)));
  o[3] = (s8)(int)fminf(1.f, fmaxf(-1.f, rintf(v.w / ws)));
  *(int*)(wq + (size_t)m * DD * DD + i) = *(const int*)o;
}

// ---------------- fused per-token absmax + int8 quant ------------------------
__global__ __launch_bounds__(256) void k_rowquant(const float* __restrict__ x, s8* __restrict__ xq,
                                                  float* __restrict__ amax) {
  int row = blockIdx.x, t = threadIdx.x;
  const float* p = x + (size_t)row * DD + t * 8;
  float4 v0 = *(const float4*)(p);
  float4 v1 = *(const float4*)(p + 4);
  float m = fmaxf(fmaxf(fmaxf(fabsf(v0.x), fabsf(v0.y)), fmaxf(fabsf(v0.z), fabsf(v0.w))),
                  fmaxf(fmaxf(fabsf(v1.x), fabsf(v1.y)), fmaxf(fabsf(v1.z), fabsf(v1.w))));
  m = fmaxf(m, __shfl_xor(m, 1));  m = fmaxf(m, __shfl_xor(m, 2));
  m = fmaxf(m, __shfl_xor(m, 4));  m = fmaxf(m, __shfl_xor(m, 8));
  m = fmaxf(m, __shfl_xor(m, 16)); m = fmaxf(m, __shfl_xor(m, 32));
  __shared__ float red[4];
  if ((t & 63) == 0) red[t >> 6] = m;
  __syncthreads();
  m = fmaxf(fmaxf(red[0], red[1]), fmaxf(red[2], red[3]));
  m = fmaxf(m, 1e-8f);                 // clip(amax, 1e-8)
  if (t == 0) amax[row] = m;
  float s = 127.0f / m;                // matches ref: QMAX / a_max
  s8 o[8];
  o[0] = (s8)(int)fminf(127.f, fmaxf(-127.f, rintf(v0.x * s)));
  o[1] = (s8)(int)fminf(127.f, fmaxf(-127.f, rintf(v0.y * s)));
  o[2] = (s8)(int)fminf(127.f, fmaxf(-127.f, rintf(v0.z * s)));
  o[3] = (s8)(int)fminf(127.f, fmaxf(-127.f, rintf(v0.w * s)));
  o[4] = (s8)(int)fminf(127.f, fmaxf(-127.f, rintf(v1.x * s)));
  o[5] = (s8)(int)fminf(127.f, fmaxf(-127.f, rintf(v1.y * s)));
  o[6] = (s8)(int)fminf(127.f, fmaxf(-127.f, rintf(v1.z * s)));
  o[7] = (s8)(int)fminf(127.f, fmaxf(-127.f, rintf(v1.w * s)));
  *(uint2*)(xq + (size_t)row * DD + t * 8) = *(const uint2*)o;
}

// ---------------- int8 MFMA GEMM: C[m][n] = sum_k A[m][k]*Bw[n][k] ----------
// Structure byte-identical to the verified round-5 phase-split schedule; only
// the element type changed (i8, BK=128 bytes/row keeps the exact same 8x16B
// slot XOR swizzle, staging counts, and vmcnt(2) ledger; 16 K-tiles).
// mfma_i32_16x16x64_i8: exact i32 accum; epilogue converts (lossless < 2^24).
template<bool OB, int NBNL>
__global__ __launch_bounds__(512) void k_gemm(const s8* __restrict__ A, const s8* __restrict__ Bw,
                                              const float* __restrict__ amax,
                                              const float* __restrict__ scales, int sbase,
                                              void* __restrict__ outv) {
  __shared__ alignas(16) u8 Asm[2][128 * 128];
  __shared__ alignas(16) u8 Bsm[2][256 * 128];
  int id = blockIdx.x;
  int xcd = id & 7, kk = id >> 3;
  int bm = kk & 31, bn = xcd * NBNL + (kk >> 5);   // bm-inner: B-panel L2-resident per XCD
  int t = threadIdx.x, w = t >> 6, l = t & 63;
  int wr = w >> 2, wc = w & 3;                     // 2M x 4N waves
  int l15 = l & 15, lh = l >> 4;
  int r0 = t >> 3;                                 // staging row (i=0); i=1 row = r0+64
  int c0 = ((t & 7) ^ (r0 & 7)) * 16;              // pre-swizzled source byte col
  const s8* Ab = A  + (size_t)(bm * 128) * DD;
  const s8* Bb = Bw + (size_t)(bn * 256) * DD;

#define STG_A(tt) do { u8* d_ = &Asm[(tt) & 1][0];                                    \
    gl_lds16(Ab + (size_t)r0 * DD + (tt) * 128 + c0,        d_ + t * 16);             \
    gl_lds16(Ab + (size_t)(r0 + 64) * DD + (tt) * 128 + c0, d_ + (512 + t) * 16); } while (0)
#define STG_B(tt, h_) do { u8* d_ = &Bsm[(tt) & 1][(h_) * 16384];                     \
    gl_lds16(Bb + (size_t)((h_) * 128 + r0) * DD + (tt) * 128 + c0,        d_ + t * 16);\
    gl_lds16(Bb + (size_t)((h_) * 128 + r0 + 64) * DD + (tt) * 128 + c0,   d_ + (512 + t) * 16); } while (0)

  i32x4 acc[4][4] = {};
  STG_A(0); STG_B(0, 0); STG_B(0, 1); STG_B(1, 0);
  asm volatile("s_waitcnt vmcnt(2)" ::: "memory");
  asm volatile("s_barrier" ::: "memory");
  for (int kb = 0; kb < 16; kb++) {
    int b = kb & 1;
    const u8* Ac = &Asm[b][0];
    const u8* Bc = &Bsm[b][0];
    // ---- phase 1: A frags + B frags j=0,1 (B-half0) ----
    i32x4 af[4][2], bf[2][2];
    #pragma unroll
    for (int i = 0; i < 4; i++)
      #pragma unroll
      for (int ks = 0; ks < 2; ks++)
        af[i][ks] = *(const i32x4*)(Ac + (wr * 64 + i * 16 + l15) * 128 + (((ks * 4 + lh) ^ (l15 & 7)) * 16));
    #pragma unroll
    for (int j = 0; j < 2; j++)
      #pragma unroll
      for (int ks = 0; ks < 2; ks++)
        bf[j][ks] = *(const i32x4*)(Bc + ((wc + 4 * j) * 16 + l15) * 128 + (((ks * 4 + lh) ^ (l15 & 7)) * 16));
    if (kb + 1 < 16) { STG_A(kb + 1); STG_B(kb + 1, 1); }
    asm volatile("s_barrier" ::: "memory");
    asm volatile("s_waitcnt lgkmcnt(0)" ::: "memory");
    __builtin_amdgcn_sched_barrier(0);
    __builtin_amdgcn_s_setprio(1);
    #pragma unroll
    for (int ks = 0; ks < 2; ks++)
      #pragma unroll
      for (int i = 0; i < 4; i++)
        #pragma unroll
        for (int j = 0; j < 2; j++)
          acc[i][j] = MFMAI8(af[i][ks], bf[j][ks], acc[i][j]);
    __builtin_amdgcn_s_setprio(0);
    asm volatile("s_barrier" ::: "memory");
    // ---- phase 2: B frags j=2,3 (B-half1) ----
    i32x4 bg[2][2];
    #pragma unroll
    for (int j = 0; j < 2; j++)
      #pragma unroll
      for (int ks = 0; ks < 2; ks++)
        bg[j][ks] = *(const i32x4*)(Bc + ((wc + 4 * (2 + j)) * 16 + l15) * 128 + (((ks * 4 + lh) ^ (l15 & 7)) * 16));
    if (kb + 2 < 16) STG_B(kb + 2, 0);
    asm volatile("s_barrier" ::: "memory");
    asm volatile("s_waitcnt lgkmcnt(0)" ::: "memory");
    __builtin_amdgcn_sched_barrier(0);
    __builtin_amdgcn_s_setprio(1);
    #pragma unroll
    for (int ks = 0; ks < 2; ks++)
      #pragma unroll
      for (int i = 0; i < 4; i++)
        #pragma unroll
        for (int j = 0; j < 2; j++)
          acc[i][2 + j] = MFMAI8(af[i][ks], bg[j][ks], acc[i][2 + j]);
    __builtin_amdgcn_s_setprio(0);
    if (kb < 14) {
      asm volatile("s_waitcnt vmcnt(2)" ::: "memory");
      asm volatile("s_barrier" ::: "memory");
    } else if (kb == 14) {
      asm volatile("s_waitcnt vmcnt(0)" ::: "memory");
      asm volatile("s_barrier" ::: "memory");
    }
  }
#undef STG_A
#undef STG_B
  int mz = OB ? (bn >> 3) : 0;
  int lcol0 = OB ? ((bn & 7) * 256) : (bn * 256);
  float wsc = scales[sbase + mz];
  u16*   outb = (u16*)outv + (size_t)mz * MM * DD;
  float* outf = (float*)outv;
  #pragma unroll
  for (int i = 0; i < 4; i++) {
    int row0 = bm * 128 + wr * 64 + i * 16 + lh * 4;
    #pragma unroll
    for (int r = 0; r < 4; r++) {
      float sc = (wsc * amax[row0 + r]) / 127.0f;
      #pragma unroll
      for (int j = 0; j < 4; j++) {
        int col = lcol0 + (wc + 4 * j) * 16 + l15;
        float y = (float)acc[i][j][r] * sc;
        if (OB) outb[(size_t)(row0 + r) * DD + col] = f2bf(y);
        else    outf[(size_t)(row0 + r) * DD + col] = y;
      }
    }
  }
}

// ---------------- V transpose: v[b*S+s][h*128+d] -> vt[(b*16+h)*128+d][s] ---
__global__ __launch_bounds__(256) void k_vtrans(const u16* __restrict__ v, u16* __restrict__ vt) {
  __shared__ u16 tile[64][72];
  int sb = blockIdx.x;           // S/64
  int db = blockIdx.y;           // HD/64
  int bh = blockIdx.z;           // B*H
  int b = bh >> 4, h = bh & 15;
  int t = threadIdx.x;
  int ls = t >> 2, ld0 = (t & 3) * 16;
  const u16* src = v + (size_t)(b * SS + sb * 64 + ls) * DD + h * HDD + db * 64 + ld0;
  *(int4*)(&tile[ls][ld0])     = *(const int4*)(src);
  *(int4*)(&tile[ls][ld0 + 8]) = *(const int4*)(src + 8);
  __syncthreads();
  int d = t >> 2, s0 = (t & 3) * 16;
  u16 tmp[16];
  #pragma unroll
  for (int k = 0; k < 16; k++) tmp[k] = tile[s0 + k][d];
  u16* dst = vt + (size_t)((bh * HDD) + db * 64 + d) * SS + sb * 64 + s0;
  *(int4*)(dst)     = *(const int4*)(tmp);
  *(int4*)(dst + 8) = *(const int4*)(tmp + 8);
}

// ---------------- causal flash attention (FROZEN from round 7) --------------
__global__ __launch_bounds__(128) void k_attn(const u16* __restrict__ Q, const u16* __restrict__ K,
                                              const u16* __restrict__ VT, float* __restrict__ O) {
  __shared__ u16 Ks[64 * 128];   // [kv][d]  256B rows, 16B slots XOR (row&15)
  __shared__ u16 Vs[128 * 64];   // [d][kv]  128B rows, 16B slots XOR (row&7)
  __shared__ u16 Ps[2 * 32 * 64]; // per-warp P[q][kv], 16B slots XOR (row&7)
  int id = blockIdx.x;
  int xcd = id & 7, rr = id >> 3;
  int bh = xcd * 4 + (rr & 3), pr = rr >> 2;       // pr = 0..15 (pair index)
  int b = bh >> 4, h = bh & 15;
  int t = threadIdx.x, w = t >> 6, l = t & 63;
  int l31 = l & 31, hi = l >> 5;
  int l15 = l & 15, lh = l >> 4;                   // 16x16 roles (PV)
  size_t base = (size_t)(b * SS) * DD + h * HDD;
  const u16* vtb = VT + (size_t)bh * HDD * SS;
  u16* Ptw = Ps + w * 2048;
  const float sc = 0.08838834764831845f;           // 1/sqrt(128)
  int ksr[8], kso[8], vsr[8], vso[8];
  #pragma unroll
  for (int i = 0; i < 8; i++) {
    int s = i * 128 + t;
    ksr[i] = s >> 4; kso[i] = ((s & 15) ^ (ksr[i] & 15)) * 8;
    vsr[i] = s >> 3; vso[i] = ((s & 7) ^ (vsr[i] & 7)) * 8;
  }
  for (int half = 0; half < 2; half++) {
    int qt = half ? (31 - pr) : pr;
    int qrow = qt * 64 + w * 32 + l31;
    bf16x8 qf[8];
    #pragma unroll
    for (int kt = 0; kt < 8; kt++)
      qf[kt] = *(const bf16x8*)(Q + base + (size_t)qrow * DD + kt * 16 + hi * 8);
    f32x4 cacc[2][8] = {};
    float mrun = -INFINITY, lrun = 0.f;
    for (int kb = 0; kb <= qt; kb++) {
      #pragma unroll
      for (int i = 0; i < 8; i++)
        gl_lds16(K + base + (size_t)(kb * 64 + ksr[i]) * DD + kso[i], Ks + (i * 128 + t) * 8);
      #pragma unroll
      for (int i = 0; i < 8; i++)
        gl_lds16(vtb + (size_t)vsr[i] * SS + kb * 64 + vso[i], Vs + (i * 128 + t) * 8);
      __syncthreads();
      // ---- S^T = K.Q^T : lane owns q-row (col=l31); kv via regs & hi ----
      f32x16 c0 = {}, c1 = {};
      #pragma unroll
      for (int kt = 0; kt < 8; kt++) {
        int sl = (((kt * 2 + hi) ^ (l31 & 15)) * 8);
        bf16x8 kf0 = *(const bf16x8*)(Ks + l31 * 128 + sl);
        bf16x8 kf1 = *(const bf16x8*)(Ks + (32 + l31) * 128 + sl);
        c0 = MFMA32(kf0, qf[kt], c0);
        c1 = MFMA32(kf1, qf[kt], c1);
      }
      if (kb == qt) {   // causal mask, diagonal tile only
        #pragma unroll
        for (int rg = 0; rg < 16; rg++) {
          int kv0 = kb * 64 + (rg & 3) + 8 * (rg >> 2) + 4 * hi;
          if (kv0 > qrow)      c0[rg] = -1e30f;
          if (kv0 + 32 > qrow) c1[rg] = -1e30f;
        }
      }
      // ---- in-register online softmax ----
      float ta[16];
      #pragma unroll
      for (int rg = 0; rg < 16; rg++) ta[rg] = fmaxf(c0[rg], c1[rg]);
      #pragma unroll
      for (int off = 8; off > 0; off >>= 1)
        #pragma unroll
        for (int rg = 0; rg < 8; rg++)
          if (rg < off) ta[rg] = fmaxf(ta[rg], ta[rg + off]);
      float pmax = fmaxf(ta[0], __shfl_xor(ta[0], 32));
      if (__any(pmax - mrun > 90.50967f)) {        // defer-max THR=8 (exp units)
        float mnew = fmaxf(mrun, pmax);
        float alpha = __expf((mrun - mnew) * sc);
        lrun *= alpha;
        #pragma unroll
        for (int m16 = 0; m16 < 2; m16++)
          #pragma unroll
          for (int r = 0; r < 4; r++) {
            float ar = __shfl(alpha, m16 * 16 + lh * 4 + r);
            #pragma unroll
            for (int n2 = 0; n2 < 8; n2++) cacc[m16][n2][r] *= ar;
          }
        mrun = mnew;
      }
      float msc = mrun * sc;
      float ts[16];
      #pragma unroll
      for (int rg = 0; rg < 16; rg++) {
        float p0 = __expf(fmaf(c0[rg], sc, -msc)); c0[rg] = p0;
        float p1 = __expf(fmaf(c1[rg], sc, -msc)); c1[rg] = p1;
        ts[rg] = p0 + p1;
      }
      #pragma unroll
      for (int off = 8; off > 0; off >>= 1)
        #pragma unroll
        for (int rg = 0; rg < 8; rg++)
          if (rg < off) ts[rg] += ts[rg + off];
      lrun += ts[0] + __shfl_xor(ts[0], 32);
      // ---- P -> per-warp LDS ----
      #pragma unroll
      for (int q4 = 0; q4 < 4; q4++) {
        uint2 pk0, pk1;
        pk0.x = (u32)f2bf(c0[4 * q4 + 0]) | ((u32)f2bf(c0[4 * q4 + 1]) << 16);
        pk0.y = (u32)f2bf(c0[4 * q4 + 2]) | ((u32)f2bf(c0[4 * q4 + 3]) << 16);
        pk1.x = (u32)f2bf(c1[4 * q4 + 0]) | ((u32)f2bf(c1[4 * q4 + 1]) << 16);
        pk1.y = (u32)f2bf(c1[4 * q4 + 2]) | ((u32)f2bf(c1[4 * q4 + 3]) << 16);
        *(uint2*)(Ptw + l31 * 64 + ((q4 ^ (l31 & 7)) * 8 + 4 * hi))       = pk0;
        *(uint2*)(Ptw + l31 * 64 + (((4 + q4) ^ (l31 & 7)) * 8 + 4 * hi)) = pk1;
      }
      // ---- PV (16x16x32): O[q][d] += P.V ----
      #pragma unroll
      for (int ks = 0; ks < 2; ks++) {
        int so = ((ks * 4 + lh) ^ (l15 & 7)) * 8;
        bf16x8 pf0 = *(const bf16x8*)(Ptw + (l15) * 64 + so);
        bf16x8 pf1 = *(const bf16x8*)(Ptw + (16 + l15) * 64 + so);
        #pragma unroll
        for (int n2 = 0; n2 < 8; n2++) {
          bf16x8 vf = *(const bf16x8*)(Vs + (n2 * 16 + l15) * 64 + so);
          cacc[0][n2] = MFMA(pf0, vf, cacc[0][n2]);
          cacc[1][n2] = MFMA(pf1, vf, cacc[1][n2]);
        }
      }
      __syncthreads();
    }
    // ---- epilogue ----
    float inv = 1.0f / lrun;
    #pragma unroll
    for (int m16 = 0; m16 < 2; m16++)
      #pragma unroll
      for (int r = 0; r < 4; r++) {
        float ir = __shfl(inv, m16 * 16 + lh * 4 + r);
        float* op = O + base + (size_t)(qt * 64 + w * 32 + m16 * 16 + lh * 4 + r) * DD;
        #pragma unroll
        for (int n2 = 0; n2 < 8; n2++)
          op[n2 * 16 + l15] = cacc[m16][n2][r] * ir;
      }
  }
}

// ---------------- launch ----------------------------------------------------
// ws layout (bytes), total ~134.4 MB:
//   0        scales (4 f32)        256      partials (1024 f64)
//   16384    amax_x                49152    amax_ctx
//   131072   w_q int8 (4 x D*D)  = 16,777,216
//   33685504 x_q int8 (M*D)      =  8,388,608   (region reused as V^T bf16, then ctx_q)
//   50462720 q bf16 | 67239936 k | 84017152 v   (16,777,216 each, contiguous)
//   100794368 ctx f32            = 33,554,432
extern "C" void kernel_launch(void* const* d_in, const int* in_sizes, int n_in,
                              void* d_out, int out_size, void* d_ws, size_t ws_size,
                              hipStream_t stream) {
  const float* x  = (const float*)d_in[0];
  const float* wq = (const float*)d_in[1];
  const float* wk = (const float*)d_in[2];
  const float* wv = (const float*)d_in[3];
  const float* wo = (const float*)d_in[4];
  char* ws = (char*)d_ws;
  float*  scales = (float*)(ws + 0);
  double* part   = (double*)(ws + 256);
  float*  amaxx  = (float*)(ws + 16384);
  float*  amaxc  = (float*)(ws + 49152);
  s8*     wqq    = (s8*)(ws + 131072);
  s8*     xq     = (s8*)(ws + 33685504);    // int8 activations; region reused as V^T, ctx_q
  u16*    vt16   = (u16*)(ws + 33685504);
  u16*    qb     = (u16*)(ws + 50462720);
  u16*    kb     = (u16*)(ws + 67239936);
  u16*    vb     = (u16*)(ws + 84017152);
  float*  ctx    = (float*)(ws + 100794368);
  (void)in_sizes; (void)n_in; (void)out_size; (void)ws_size;

  k_wabs_partial<<<1024, 256, 0, stream>>>(wq, wk, wv, wo, part);
  k_wscale_final<<<1, 64, 0, stream>>>(part, scales);
  k_wquant<<<dim3(4096, 4), 256, 0, stream>>>(wq, wk, wv, wo, wqq, scales);
  k_rowquant<<<MM, 256, 0, stream>>>(x, xq, amaxx);
  k_gemm<true, 3><<<768, 512, 0, stream>>>(xq, wqq, amaxx, scales, 0, (void*)qb);
  k_vtrans<<<dim3(32, 2, 32), 256, 0, stream>>>(vb, vt16);
  k_attn<<<512, 128, 0, stream>>>(qb, kb, vt16, ctx);
  k_rowquant<<<MM, 256, 0, stream>>>(ctx, xq, amaxc);   // ctx_q overwrites V^T
  k_gemm<false, 1><<<256, 512, 0, stream>>>(xq, wqq + (size_t)3 * DD * DD, amaxc, scales, 3, d_out);
}